// Round 5
// baseline (63.104 us; speedup 1.0000x reference)
//
#include <hip/hip_runtime.h>
#include <math.h>

#define BB 4
#define NN 512
#define PP 2048
#define EE 32768
#define FH 128
#define DRBF 32
#define INDIM 416
#define CUT 4.0f
#define PI_F 3.14159265358979323846f
#define NMAX 8192            // cap on surviving edges (observed n ~ 1300)

struct __align__(16) Rec { float dx, dy, dz; unsigned int ap; };

// d_ws layout (bytes):
//   [0)      cnt (int)
//   [256)    recs: NMAX * 16
//   [256+NMAX*16)          cwA: NMAX * 4
//   [256+NMAX*16+NMAX*4)   pA:  NMAX * 4
//   [1<<20)  HT:  416 * NMAX * 4   (~13.6 MB)
//   [16<<20) H2T: 128 * NMAX * 4   (~4.2 MB)

__global__ __launch_bounds__(256) void init_kernel(float* __restrict__ out, int* __restrict__ cnt) {
  int idx = blockIdx.x * blockDim.x + threadIdx.x;
  if (idx < BB * PP) out[idx] = 0.0f;
  if (idx == 0) *cnt = 0;
}

__global__ __launch_bounds__(256) void filter_kernel(
    const int* __restrict__ pe, const float* __restrict__ pdisp,
    const float* __restrict__ cell, const float* __restrict__ atom_xyz,
    const float* __restrict__ probe_xyz, int* __restrict__ cnt, Rec* __restrict__ recs) {
  int e = blockIdx.x * blockDim.x + threadIdx.x;   // grid covers exactly B*E
  int b = e >> 15;
  int2 ap = ((const int2*)pe)[e];
  float pd0 = pdisp[e*3], pd1 = pdisp[e*3+1], pd2 = pdisp[e*3+2];
  const float* cb = cell + b*9;
  float d0 = pd0*cb[0] + pd1*cb[3] + pd2*cb[6];
  float d1 = pd0*cb[1] + pd1*cb[4] + pd2*cb[7];
  float d2 = pd0*cb[2] + pd1*cb[5] + pd2*cb[8];
  int ag = b*NN + ap.x;
  int pg = b*PP + ap.y;
  float dx = probe_xyz[pg*3]   - (atom_xyz[ag*3]   + d0);
  float dy = probe_xyz[pg*3+1] - (atom_xyz[ag*3+1] + d1);
  float dz = probe_xyz[pg*3+2] - (atom_xyz[ag*3+2] + d2);
  float dist2 = dx*dx + dy*dy + dz*dz;
  if (dist2 < CUT*CUT) {
    int i = atomicAdd(cnt, 1);
    if (i < NMAX) {
      Rec r; r.dx = dx; r.dy = dy; r.dz = dz;
      r.ap = ((unsigned)ag << 16) | (unsigned)pg;
      recs[i] = r;
    }
  }
}

// Build HT[k][edge] (k-major, stride NMAX) + cwA/pA. Block = 4 waves = 4 edges.
__global__ __launch_bounds__(256) void gather_kernel(
    const Rec* __restrict__ recs, const int* __restrict__ cnt,
    const float* __restrict__ S, const float* __restrict__ V,
    float* __restrict__ HT, float* __restrict__ cwA, int* __restrict__ pA) {
  __shared__ float hS[4][420];
  const int tid  = threadIdx.x;
  const int lane = tid & 63;
  const int wave = tid >> 6;
  int n = *cnt; if (n > NMAX) n = NMAX;
  const int bt = blockIdx.x;
  if (bt * 4 >= n) return;

  const int eg = bt * 4 + wave;
  Rec r;
  if (eg < n) r = recs[eg];
  else { r.dx = 1.0f; r.dy = 0.0f; r.dz = 0.0f; r.ap = 0u; }
  unsigned a = r.ap >> 16;
  const float2* Vf2 = (const float2*)V;
  const float2* Sf2 = (const float2*)S;
  float2 v0 = Vf2[(a*3+0)*64 + lane];
  float2 v1 = Vf2[(a*3+1)*64 + lane];
  float2 v2 = Vf2[(a*3+2)*64 + lane];
  float2 sj = Sf2[a*64 + lane];
  float d = sqrtf(r.dx*r.dx + r.dy*r.dy + r.dz*r.dz);
  float inv = 1.0f / (d + 1e-8f);
  float rh0 = r.dx*inv, rh1 = r.dy*inv, rh2 = r.dz*inv;
  if (lane < DRBF) hS[wave][lane] = sinf(d * (float)(lane+1) * (PI_F/CUT)) / d;
  float2 q;  q.x  = v0.x*rh0 + v1.x*rh1 + v2.x*rh2;
             q.y  = v0.y*rh0 + v1.y*rh1 + v2.y*rh2;
  float2 nv; nv.x = sqrtf(v0.x*v0.x + v1.x*v1.x + v2.x*v2.x);
             nv.y = sqrtf(v0.y*v0.y + v1.y*v1.y + v2.y*v2.y);
  *(float2*)&hS[wave][DRBF        + 2*lane] = q;
  *(float2*)&hS[wave][DRBF +   FH + 2*lane] = nv;
  *(float2*)&hS[wave][DRBF + 2*FH + 2*lane] = sj;
  if (lane == 0 && eg < n) {
    cwA[eg] = 0.5f * (cosf((PI_F/CUT) * d) + 1.0f);
    pA[eg]  = (int)(r.ap & 0xFFFFu);
  }
  __syncthreads();

  // coalesced-ish transpose write: HT[k][bt*4+e]
  for (int i = tid; i < INDIM * 4; i += 256) {
    int k = i >> 2, e = i & 3;
    if (bt * 4 + e < n) HT[k * NMAX + bt * 4 + e] = hS[e][k];
  }
}

// Layer 1: 1-wave blocks. block -> (edge-block eb, feature-block fb of 8).
// lane = edge. Weights are wave-uniform -> scalar loads; h reads coalesced.
__global__ __launch_bounds__(64) void mlp1_kernel(
    const float* __restrict__ HT, const int* __restrict__ cnt,
    const float* __restrict__ W1, const float* __restrict__ b1,
    float* __restrict__ H2T) {
  int n = *cnt; if (n > NMAX) n = NMAX;
  const int eb = blockIdx.x >> 4;
  const int fb = blockIdx.x & 15;
  if (eb * 64 >= n) return;
  const int edge = eb * 64 + threadIdx.x;
  const bool act = edge < n;
  const int ecl = act ? edge : eb * 64;   // inactive lanes read a valid column

  float acc[8];
  #pragma unroll
  for (int j = 0; j < 8; ++j) acc[j] = b1[fb*8 + j];

  const float* __restrict__ hp = HT + ecl;
  const float* __restrict__ wp = W1 + fb*8;
  #pragma unroll 16
  for (int k = 0; k < INDIM; ++k) {
    float hv = hp[k * NMAX];
    const float* wr = wp + k * FH;        // wave-uniform -> s_load
    #pragma unroll
    for (int j = 0; j < 8; ++j) acc[j] = fmaf(hv, wr[j], acc[j]);
  }
  if (act) {
    #pragma unroll
    for (int j = 0; j < 8; ++j) {
      float h1 = acc[j] / (1.0f + __expf(-acc[j]));
      H2T[(fb*8 + j) * NMAX + edge] = h1;
    }
  }
}

// Layer 2 + folded layer 3 + cutoff + scatter. block -> (eb, out-block fb2 of 8).
__global__ __launch_bounds__(64) void mlp2_kernel(
    const float* __restrict__ H2T, const int* __restrict__ cnt,
    const float* __restrict__ W2, const float* __restrict__ b2,
    const float* __restrict__ W3, const float* __restrict__ b3,
    const float* __restrict__ cwA, const int* __restrict__ pA,
    float* __restrict__ out) {
  int n = *cnt; if (n > NMAX) n = NMAX;
  const int eb  = blockIdx.x >> 3;
  const int fb2 = blockIdx.x & 7;
  if (eb * 64 >= n) return;
  const int edge = eb * 64 + threadIdx.x;
  const bool act = edge < n;
  const int ecl = act ? edge : eb * 64;

  float acc[8];
  #pragma unroll
  for (int j = 0; j < 8; ++j) acc[j] = b2[fb2*8 + j];

  const float* __restrict__ hp = H2T + ecl;
  const float* __restrict__ wp = W2 + fb2*8;
  #pragma unroll 16
  for (int k = 0; k < FH; ++k) {
    float hv = hp[k * NMAX];
    const float* wr = wp + k * 64;        // wave-uniform -> s_load
    #pragma unroll
    for (int j = 0; j < 8; ++j) acc[j] = fmaf(hv, wr[j], acc[j]);
  }
  float partial = 0.0f;
  #pragma unroll
  for (int j = 0; j < 8; ++j) {
    float h2 = acc[j] / (1.0f + __expf(-acc[j]));
    partial = fmaf(h2, W3[fb2*8 + j], partial);
  }
  if (fb2 == 0) partial += b3[0];
  if (act) atomicAdd(&out[pA[edge]], partial * cwA[edge]);
}

extern "C" void kernel_launch(void* const* d_in, const int* in_sizes, int n_in,
                              void* d_out, int out_size, void* d_ws, size_t ws_size,
                              hipStream_t stream) {
  const float* S         = (const float*)d_in[0];
  const float* V         = (const float*)d_in[1];
  const float* atom_xyz  = (const float*)d_in[2];
  const float* probe_xyz = (const float*)d_in[3];
  const float* cell      = (const float*)d_in[4];
  const float* pdisp     = (const float*)d_in[5];
  const float* W1        = (const float*)d_in[6];
  const float* b1        = (const float*)d_in[7];
  const float* W2        = (const float*)d_in[8];
  const float* b2        = (const float*)d_in[9];
  const float* W3        = (const float*)d_in[10];
  const float* b3        = (const float*)d_in[11];
  const int*   pe        = (const int*)d_in[12];
  float* out = (float*)d_out;

  char* ws = (char*)d_ws;
  int*   cnt  = (int*)ws;
  Rec*   recs = (Rec*)(ws + 256);
  float* cwA  = (float*)(ws + 256 + NMAX*16);
  int*   pA   = (int*)(ws + 256 + NMAX*16 + NMAX*4);
  float* HT   = (float*)(ws + (1u  << 20));
  float* H2T  = (float*)(ws + (16u << 20));

  init_kernel<<<32, 256, 0, stream>>>(out, cnt);
  filter_kernel<<<BB*EE/256, 256, 0, stream>>>(pe, pdisp, cell, atom_xyz, probe_xyz, cnt, recs);
  gather_kernel<<<NMAX/4, 256, 0, stream>>>(recs, cnt, S, V, HT, cwA, pA);
  mlp1_kernel<<<(NMAX/64)*16, 64, 0, stream>>>(HT, cnt, W1, b1, H2T);
  mlp2_kernel<<<(NMAX/64)*8, 64, 0, stream>>>(H2T, cnt, W2, b2, W3, b3, cwA, pA, out);
}